// Round 6
// baseline (989.485 us; speedup 1.0000x reference)
//
#include <hip/hip_runtime.h>

#define MDIM 8192   // B*S
#define KDIM 4096   // DIN
#define NDIM 11008  // DOUT

#define NBLK_W 1024
#define NBLK_X 2048

typedef float f32x4 __attribute__((ext_vector_type(4)));
typedef short bf16x8 __attribute__((ext_vector_type(8)));
typedef unsigned short us4 __attribute__((ext_vector_type(4)));
typedef unsigned short us8 __attribute__((ext_vector_type(8)));

#define GAS __attribute__((address_space(1)))
#define LAS __attribute__((address_space(3)))

__device__ __forceinline__ unsigned short f2bf(float f) {
  unsigned int u = __builtin_bit_cast(unsigned int, f);
  u += 0x7FFFu + ((u >> 16) & 1u);   // RTNE
  return (unsigned short)(u >> 16);
}

// --- Kernel 1: sign(W) -> +-1.0 bf16, fused with |W| partial reduction ---
__global__ __launch_bounds__(256) void k_convert_w(const float* __restrict__ w,
                                                   unsigned short* __restrict__ wq,
                                                   float* __restrict__ partials) {
  const int n4 = (NDIM * KDIM) / 4;
  const int stride = gridDim.x * blockDim.x;
  float s = 0.f;
  for (int i = blockIdx.x * blockDim.x + threadIdx.x; i < n4; i += stride) {
    f32x4 v = ((const f32x4*)w)[i];
    s += fabsf(v.x) + fabsf(v.y) + fabsf(v.z) + fabsf(v.w);
    us4 q;
    q.x = v.x > 0.f ? 0x3F80u : (v.x < 0.f ? 0xBF80u : 0u);
    q.y = v.y > 0.f ? 0x3F80u : (v.y < 0.f ? 0xBF80u : 0u);
    q.z = v.z > 0.f ? 0x3F80u : (v.z < 0.f ? 0xBF80u : 0u);
    q.w = v.w > 0.f ? 0x3F80u : (v.w < 0.f ? 0xBF80u : 0u);
    ((us4*)wq)[i] = q;
  }
  #pragma unroll
  for (int off = 32; off > 0; off >>= 1) s += __shfl_down(s, off, 64);
  __shared__ float red[4];
  if ((threadIdx.x & 63) == 0) red[threadIdx.x >> 6] = s;
  __syncthreads();
  if (threadIdx.x == 0) partials[blockIdx.x] = red[0] + red[1] + red[2] + red[3];
}

// --- Kernel 2: deterministic final reduction -> scale ---
__global__ __launch_bounds__(256) void k_scale(const float* __restrict__ partials,
                                               float* __restrict__ scale) {
  float s = 0.f;
  for (int i = threadIdx.x; i < NBLK_W; i += 256) s += partials[i];
  #pragma unroll
  for (int off = 32; off > 0; off >>= 1) s += __shfl_down(s, off, 64);
  __shared__ float red[4];
  if ((threadIdx.x & 63) == 0) red[threadIdx.x >> 6] = s;
  __syncthreads();
  if (threadIdx.x == 0)
    *scale = (red[0] + red[1] + red[2] + red[3]) / (float)((size_t)NDIM * KDIM);
}

// --- Kernel 3: x fp32 -> bf16 ---
__global__ __launch_bounds__(256) void k_convert_x(const float* __restrict__ x,
                                                   unsigned short* __restrict__ xb) {
  const int n8 = (MDIM * KDIM) / 8;
  const int stride = gridDim.x * blockDim.x;
  for (int i = blockIdx.x * blockDim.x + threadIdx.x; i < n8; i += stride) {
    f32x4 v0 = ((const f32x4*)x)[2 * i];
    f32x4 v1 = ((const f32x4*)x)[2 * i + 1];
    us8 q;
    q[0] = f2bf(v0.x); q[1] = f2bf(v0.y); q[2] = f2bf(v0.z); q[3] = f2bf(v0.w);
    q[4] = f2bf(v1.x); q[5] = f2bf(v1.y); q[6] = f2bf(v1.z); q[7] = f2bf(v1.w);
    ((us8*)xb)[i] = q;
  }
}

// --- Kernel 4: 256x256 8-phase bf16 MFMA GEMM ---
// ROUND-4 PROVEN SHAPE (reads->stage->BAR->LGKM0->MFMA->BAR, VM ledger) with ONE
// change: every frag ds_read issues exactly ONE phase before consumption, placed
// AFTER the current phase's LGKM0 and pinned (SB0) before the MFMA cluster ->
// reads overlap the MFMA cluster + barrier; next phase's LGKM0 is ~free.
// Quadrant order per K-tile: q0(afL,bq01) q1(afL,bq23) q2(afH,bq01) q3(afH,bq23)
//   -> every reload's target regs have last-use >= 1 phase before reload issue:
//   issue map: g0:bq23(b0) g1:afH(b0) g2:- g3:afL+bq01(b1) g4:bq23(b1) g5:afH(b1)
//              g6:- g7:afL+bq01(b0,next). Frags single-buffered: 96 VGPR.
// Stage slots (unchanged): g0/g1 buf1.A<-K(2i+1); g2/g3 buf0.B<-K(2i+2);
//   g4/g5 buf0.A<-K(2i+2); g6/g7 buf1.B<-K(2i+3).
// VM(4) at g3/g7 TOPS (before BAR): at g3 drains prev-g6,g7 (buf1.B) + g0,g1
//   (buf1.A) -> buf1 complete before its reads issue after the BAR; symmetric g7.
// Write-after-read: every region's reads drain at a LGKM0 >= 1 barrier before
//   the overwriting stage (checked per-region). No other VMEM in loop (no spill).

#define BAR()  __builtin_amdgcn_s_barrier()
#define SB0()  __builtin_amdgcn_sched_barrier(0)
#define PRIO1() __builtin_amdgcn_s_setprio(1)
#define PRIO0() __builtin_amdgcn_s_setprio(0)
#define LGKM(N) do { asm volatile("s_waitcnt lgkmcnt(" #N ")" ::: "memory"); SB0(); } while (0)
#define VM(N)   do { asm volatile("s_waitcnt vmcnt(" #N ")" ::: "memory"); SB0(); } while (0)

#define STAGE(GP, ROWB, LDSOFF, HALF, KT) do {                                        \
  const unsigned short* _s = (GP) + (size_t)((ROWB) + (HALF)*128 + srow) * KDIM       \
                              + (KT)*64 + scol;                                       \
  unsigned short* _d = lds + (LDSOFF) + (HALF)*8192 + tid*8;                          \
  __builtin_amdgcn_global_load_lds((const GAS unsigned int*)_s,                       \
                                   (LAS unsigned int*)_d, 16, 0, 0);                  \
  __builtin_amdgcn_global_load_lds((const GAS unsigned int*)(_s + (size_t)64*KDIM),   \
                                   (LAS unsigned int*)(_d + 4096), 16, 0, 0);         \
} while (0)

// B col-group pair: DST[ni][kk] for output cols wn*64 + (NB+ni)*16 + l15
#define LOAD_B2(DST, BUF, NB)                                                         \
  _Pragma("unroll") for (int ni = 0; ni < 2; ++ni)                                    \
  _Pragma("unroll") for (int kk = 0; kk < 2; ++kk)                                    \
    DST[ni][kk] = *(const bf16x8*)&lds[(BUF)*32768 + 16384 + bWOff + ((NB)+ni)*1024   \
                                       + rowoff + rcol[kk]];

// A quarter (64 rows) of this wave's half: MQ=0 rows 0..63, MQ=1 rows 64..127
#define LOAD_A(DST, BUF, MQ)                                                          \
  _Pragma("unroll") for (int mi = 0; mi < 4; ++mi)                                    \
  _Pragma("unroll") for (int kk = 0; kk < 2; ++kk)                                    \
    DST[mi][kk] = *(const bf16x8*)&lds[(BUF)*32768 + aWOff + (MQ)*4096 + mi*1024      \
                                       + rowoff + rcol[kk]];

// 16 MFMA: 4 mi x 2 ni x 2 kk -> acc[MB+mi][NB+ni]
#define MFMA16(AF, MB, BQ, NB)                                                        \
  _Pragma("unroll") for (int kk = 0; kk < 2; ++kk)                                    \
  _Pragma("unroll") for (int mi = 0; mi < 4; ++mi)                                    \
  _Pragma("unroll") for (int ni = 0; ni < 2; ++ni)                                    \
    acc[(MB)+mi][(NB)+ni] = __builtin_amdgcn_mfma_f32_16x16x32_bf16(                  \
        AF[mi][kk], BQ[ni][kk], acc[(MB)+mi][(NB)+ni], 0, 0, 0);

__global__ __launch_bounds__(512, 2) void k_gemm256(const unsigned short* __restrict__ A,
                                                    const unsigned short* __restrict__ B,
                                                    const float* __restrict__ bias,
                                                    const float* __restrict__ scale_p,
                                                    float* __restrict__ C) {
  extern __shared__ unsigned short lds[];

  const int nTn = NDIM / 256;                  // 43
  const int nwg = (MDIM / 256) * nTn;          // 1376 (== 0 mod 8)
  int wg = (int)blockIdx.x;
  wg = (wg & 7) * (nwg / 8) + (wg >> 3);       // XCD-aware swizzle (bijective)
  const int tm = wg / nTn;
  const int tn = wg % nTn;

  const int tid  = (int)threadIdx.x;
  const int lane = tid & 63;
  const int wave = tid >> 6;                   // 0..7
  const int wm   = wave >> 2;                  // 0..1  (M)
  const int wn   = wave & 3;                   // 0..3  (N)
  const int l15  = lane & 15;

  // read-side: row = l15 (+16-multiples), col = (hi*8 + kk*32) ^ ((l15&7)<<3)
  const int rowoff = l15 * 64;
  const int rsw = (l15 & 7) << 3;
  int rcol[2];
  rcol[0] = ((lane >> 4) * 8) ^ rsw;
  rcol[1] = ((lane >> 4) * 8 + 32) ^ rsw;
  // stage-side: LDS linear dest; pre-swizzled GLOBAL source column (rule #21)
  const int scol = ((tid & 7) * 8) ^ (((tid >> 3) & 7) << 3);
  const int srow = tid >> 3;                   // 0..63

  const int aWOff = wm * 8192;                             // this wave's A half
  const int bWOff = (wn >> 1) * 8192 + (wn & 1) * 4096;    // this wave's 64-row B chunk
  const int aRow = tm * 256;
  const int bRow = tn * 256;

  f32x4 acc[8][4];
  #pragma unroll
  for (int i = 0; i < 8; ++i)
    #pragma unroll
    for (int j = 0; j < 4; ++j) acc[i][j] = f32x4{0.f, 0.f, 0.f, 0.f};

  bf16x8 afL[4][2], afH[4][2], bq01[2][2], bq23[2][2];

  // ---- prologue: buf0 <- K0 (B,A); buf1.B <- K1; pre-issue g0's frags ----
  STAGE(B, bRow, 16384, 0, 0);
  STAGE(B, bRow, 16384, 1, 0);
  STAGE(A, aRow, 0,     0, 0);
  STAGE(A, aRow, 0,     1, 0);
  STAGE(B, bRow, 49152, 0, 1);
  STAGE(B, bRow, 49152, 1, 1);
  VM(4);                                        // drains buf0 K0 (leaves buf1.B in flight)
  BAR();
  LOAD_A(afL, 0, 0); LOAD_B2(bq01, 0, 0);       // frags for g0

  #pragma unroll 1
  for (int i = 0; i < 32; ++i) {
    const int kA = 2 * i + 1;                            // <= 63
    const int kB = (2 * i + 2 > 63) ? 63 : 2 * i + 2;    // clamped tail
    const int kC = (2 * i + 3 > 63) ? 63 : 2 * i + 3;
    // g0: MFMA(afL,bq01)@buf0; issue bq23(buf0) for g1; stage buf1.A.h0 <- kA
    STAGE(A, aRow, 32768, 0, kA);
    BAR(); LGKM(0);
    LOAD_B2(bq23, 0, 2); SB0();
    PRIO1(); MFMA16(afL, 0, bq01, 0); PRIO0(); SB0(); BAR();
    // g1: MFMA(afL,bq23); issue afH(buf0) for g2; stage buf1.A.h1 <- kA
    STAGE(A, aRow, 32768, 1, kA);
    BAR(); LGKM(0);
    LOAD_A(afH, 0, 1); SB0();
    PRIO1(); MFMA16(afL, 0, bq23, 2); PRIO0(); SB0(); BAR();
    // g2: MFMA(afH,bq01); no reads (g3's operands already live); stage buf0.B.h0 <- kB
    STAGE(B, bRow, 16384, 0, kB);
    BAR(); LGKM(0);
    PRIO1(); MFMA16(afH, 4, bq01, 0); PRIO0(); SB0(); BAR();
    // g3: VM(4) lands buf1(K 2i+1); MFMA(afH,bq23); issue afL+bq01(buf1) for g4;
    //     stage buf0.B.h1 <- kB
    STAGE(B, bRow, 16384, 1, kB);
    VM(4);
    BAR(); LGKM(0);
    LOAD_A(afL, 1, 0); LOAD_B2(bq01, 1, 0); SB0();
    PRIO1(); MFMA16(afH, 4, bq23, 2); PRIO0(); SB0(); BAR();
    // g4: MFMA(afL,bq01)@buf1; issue bq23(buf1) for g5; stage buf0.A.h0 <- kB
    STAGE(A, aRow, 0, 0, kB);
    BAR(); LGKM(0);
    LOAD_B2(bq23, 1, 2); SB0();
    PRIO1(); MFMA16(afL, 0, bq01, 0); PRIO0(); SB0(); BAR();
    // g5: MFMA(afL,bq23); issue afH(buf1) for g6; stage buf0.A.h1 <- kB
    STAGE(A, aRow, 0, 1, kB);
    BAR(); LGKM(0);
    LOAD_A(afH, 1, 1); SB0();
    PRIO1(); MFMA16(afL, 0, bq23, 2); PRIO0(); SB0(); BAR();
    // g6: MFMA(afH,bq01); no reads; stage buf1.B.h0 <- kC
    STAGE(B, bRow, 49152, 0, kC);
    BAR(); LGKM(0);
    PRIO1(); MFMA16(afH, 4, bq01, 0); PRIO0(); SB0(); BAR();
    // g7: VM(4) lands buf0(K 2i+2); MFMA(afH,bq23); issue afL+bq01(buf0) for next g0;
    //     stage buf1.B.h1 <- kC
    STAGE(B, bRow, 49152, 1, kC);
    VM(4);
    BAR(); LGKM(0);
    LOAD_A(afL, 0, 0); LOAD_B2(bq01, 0, 0); SB0();
    PRIO1(); MFMA16(afH, 4, bq23, 2); PRIO0(); SB0(); BAR();
  }

  VM(0);    // drain tail prefetch stages
  LGKM(0);  // drain stray last-g7 frag reads

  const float sc = *scale_p;
  float bv[4];
  #pragma unroll
  for (int ni = 0; ni < 4; ++ni) bv[ni] = bias[tn * 256 + wn * 64 + ni * 16 + l15];

  // C/D layout: col = lane&15, row = (lane>>4)*4 + reg
  #pragma unroll
  for (int mi = 0; mi < 8; ++mi) {
    #pragma unroll
    for (int r = 0; r < 4; ++r) {
      const int m = tm * 256 + wm * 128 + mi * 16 + (lane >> 4) * 4 + r;
      float* crow = C + (size_t)m * NDIM + tn * 256 + wn * 64;
      #pragma unroll
      for (int ni = 0; ni < 4; ++ni)
        crow[ni * 16 + l15] = sc * acc[mi][ni][r] + bv[ni];
    }
  }
}

extern "C" void kernel_launch(void* const* d_in, const int* in_sizes, int n_in,
                              void* d_out, int out_size, void* d_ws, size_t ws_size,
                              hipStream_t stream) {
  const float* x = (const float*)d_in[0];
  const float* w = (const float*)d_in[1];
  const float* bias = (const float*)d_in[2];
  float* out = (float*)d_out;

  char* ws = (char*)d_ws;
  const size_t XB_BYTES = (size_t)MDIM * KDIM * 2;
  const size_t WQ_BYTES = (size_t)NDIM * KDIM * 2;
  unsigned short* xb = (unsigned short*)ws;
  unsigned short* wq = (unsigned short*)(ws + XB_BYTES);
  float* partials = (float*)(ws + XB_BYTES + WQ_BYTES);
  float* scale = partials + NBLK_W;

  k_convert_w<<<NBLK_W, 256, 0, stream>>>(w, wq, partials);
  k_scale<<<1, 256, 0, stream>>>(partials, scale);
  k_convert_x<<<NBLK_X, 256, 0, stream>>>(x, xb);

  (void)hipFuncSetAttribute((const void*)k_gemm256,
                            hipFuncAttributeMaxDynamicSharedMemorySize, 131072);
  const int grid = (MDIM / 256) * (NDIM / 256);  // 1376
  k_gemm256<<<grid, 512, 131072, stream>>>(xb, wq, bias, scale, out);
}

// Round 7
// 712.490 us; speedup vs baseline: 1.3888x; 1.3888x over previous
//
#include <hip/hip_runtime.h>

#define MDIM 8192   // B*S
#define KDIM 4096   // DIN
#define NDIM 11008  // DOUT

#define NBLK_W 1024
#define NBLK_X 2048

typedef float f32x4 __attribute__((ext_vector_type(4)));
typedef short bf16x8 __attribute__((ext_vector_type(8)));
typedef unsigned short us4 __attribute__((ext_vector_type(4)));
typedef unsigned short us8 __attribute__((ext_vector_type(8)));

#define GAS __attribute__((address_space(1)))
#define LAS __attribute__((address_space(3)))

__device__ __forceinline__ unsigned short f2bf(float f) {
  unsigned int u = __builtin_bit_cast(unsigned int, f);
  u += 0x7FFFu + ((u >> 16) & 1u);   // RTNE
  return (unsigned short)(u >> 16);
}

// --- Kernel 1: sign(W) -> +-1.0 bf16, fused with |W| partial reduction ---
__global__ __launch_bounds__(256) void k_convert_w(const float* __restrict__ w,
                                                   unsigned short* __restrict__ wq,
                                                   float* __restrict__ partials) {
  const int n4 = (NDIM * KDIM) / 4;
  const int stride = gridDim.x * blockDim.x;
  float s = 0.f;
  for (int i = blockIdx.x * blockDim.x + threadIdx.x; i < n4; i += stride) {
    f32x4 v = ((const f32x4*)w)[i];
    s += fabsf(v.x) + fabsf(v.y) + fabsf(v.z) + fabsf(v.w);
    us4 q;
    q.x = v.x > 0.f ? 0x3F80u : (v.x < 0.f ? 0xBF80u : 0u);
    q.y = v.y > 0.f ? 0x3F80u : (v.y < 0.f ? 0xBF80u : 0u);
    q.z = v.z > 0.f ? 0x3F80u : (v.z < 0.f ? 0xBF80u : 0u);
    q.w = v.w > 0.f ? 0x3F80u : (v.w < 0.f ? 0xBF80u : 0u);
    ((us4*)wq)[i] = q;
  }
  #pragma unroll
  for (int off = 32; off > 0; off >>= 1) s += __shfl_down(s, off, 64);
  __shared__ float red[4];
  if ((threadIdx.x & 63) == 0) red[threadIdx.x >> 6] = s;
  __syncthreads();
  if (threadIdx.x == 0) partials[blockIdx.x] = red[0] + red[1] + red[2] + red[3];
}

// --- Kernel 2: deterministic final reduction -> scale ---
__global__ __launch_bounds__(256) void k_scale(const float* __restrict__ partials,
                                               float* __restrict__ scale) {
  float s = 0.f;
  for (int i = threadIdx.x; i < NBLK_W; i += 256) s += partials[i];
  #pragma unroll
  for (int off = 32; off > 0; off >>= 1) s += __shfl_down(s, off, 64);
  __shared__ float red[4];
  if ((threadIdx.x & 63) == 0) red[threadIdx.x >> 6] = s;
  __syncthreads();
  if (threadIdx.x == 0)
    *scale = (red[0] + red[1] + red[2] + red[3]) / (float)((size_t)NDIM * KDIM);
}

// --- Kernel 3: x fp32 -> bf16 ---
__global__ __launch_bounds__(256) void k_convert_x(const float* __restrict__ x,
                                                   unsigned short* __restrict__ xb) {
  const int n8 = (MDIM * KDIM) / 8;
  const int stride = gridDim.x * blockDim.x;
  for (int i = blockIdx.x * blockDim.x + threadIdx.x; i < n8; i += stride) {
    f32x4 v0 = ((const f32x4*)x)[2 * i];
    f32x4 v1 = ((const f32x4*)x)[2 * i + 1];
    us8 q;
    q[0] = f2bf(v0.x); q[1] = f2bf(v0.y); q[2] = f2bf(v0.z); q[3] = f2bf(v0.w);
    q[4] = f2bf(v1.x); q[5] = f2bf(v1.y); q[6] = f2bf(v1.z); q[7] = f2bf(v1.w);
    ((us8*)xb)[i] = q;
  }
}

// --- Kernel 4: 256x256 8-phase bf16 MFMA GEMM (r4 shape, relaxed drain) ---
// C[m][n] = scale * sum_k A[m][k]*Bq[n][k] + bias[n]
// 8 waves (2M x 4N), per-wave 128x64, BK=64, 2 K-tiles/iter, 8 phases/iter.
// Phase: {frag ds_reads; stage (2 global_load_lds); BAR; MFMA x16; BAR}.
// CHANGE vs r4 (690us, MfmaUtil 48): NO explicit lgkmcnt(0)+sched_barrier drain
// after the phase barrier. Frag reads are C-level loads, so LLVM's waitcnt pass
// emits per-MFMA lgkmcnt(N) -> the MFMA cluster starts when its FIRST operands
// land and later reads complete under earlier MFMAs (pipelined, not serial).
// Quadrant order per K-tile: (Alow,B01)(Alow,B23)(Ahigh,B23)(Ahigh,B01)
//   -> one af[4][2] reused for both A halves; frag liveness 96 VGPR max.
// LDS 128 KiB (shorts): buf0{A:0,B:16384} buf1{A:32768,B:49152}, half=8192.
// Stage slots: g0/g1 buf1.A<-K(2i+1); g2/g3 buf0.B<-K(2i+2); g4/g5 buf0.A<-K(2i+2);
//              g6/g7 buf1.B<-K(2i+3). Counted VM(4) at g3/g7 end, never 0 in-loop.
// VM ledger (verified, r4-proven): at g3, outstanding = prev{g6,g7}(buf1.B) +
//   {g0,g1}(buf1.A) + {g2,g3}(buf0.B) = 12 -> VM(4) drains buf1 fully before g4's
//   buf1 reads; symmetric at g7 for buf0 before next g0. "memory" clobber on the
//   VM asm keeps subsequent LDS reads ordered after it.
// WAR: each region's readers are consumed (compiler waitcnt before their MFMA)
//   >= 1 end-of-phase barrier before the overwriting stage issues. Cross-wave
//   safe: a wave passes the barrier only after its consuming MFMAs issued, which
//   forces its reads complete. No other VMEM in loop (no spill at 128 VGPR).
//
// SWIZZLE: 3-bit XOR inside the 64-short row. LDS(row,c) holds
//   G(row, c ^ ((row&7)<<3)); read col = (hi*8 + kk*32) ^ ((l15&7)<<3) (kk folded
//   INSIDE the XOR). Bank-conflict = 0 (verified r4: SQ_LDS_BANK_CONFLICT 2.7e8->0).

#define BAR()  __builtin_amdgcn_s_barrier()
#define SB0()  __builtin_amdgcn_sched_barrier(0)
#define PRIO1() __builtin_amdgcn_s_setprio(1)
#define PRIO0() __builtin_amdgcn_s_setprio(0)
#define VM(N)  asm volatile("s_waitcnt vmcnt(" #N ")" ::: "memory")

#define STAGE(GP, ROWB, LDSOFF, HALF, KT) do {                                        \
  const unsigned short* _s = (GP) + (size_t)((ROWB) + (HALF)*128 + srow) * KDIM       \
                              + (KT)*64 + scol;                                       \
  unsigned short* _d = lds + (LDSOFF) + (HALF)*8192 + tid*8;                          \
  __builtin_amdgcn_global_load_lds((const GAS unsigned int*)_s,                       \
                                   (LAS unsigned int*)_d, 16, 0, 0);                  \
  __builtin_amdgcn_global_load_lds((const GAS unsigned int*)(_s + (size_t)64*KDIM),   \
                                   (LAS unsigned int*)(_d + 4096), 16, 0, 0);         \
} while (0)

// B col-group pair: DST[ni][kk] for output cols wn*64 + (NB+ni)*16 + l15
#define LOAD_B2(DST, BUF, NB)                                                         \
  _Pragma("unroll") for (int ni = 0; ni < 2; ++ni)                                    \
  _Pragma("unroll") for (int kk = 0; kk < 2; ++kk)                                    \
    DST[ni][kk] = *(const bf16x8*)&lds[(BUF)*32768 + 16384 + bWOff + ((NB)+ni)*1024   \
                                       + rowoff + rcol[kk]];

// A quarter (64 rows) of this wave's half: MQ=0 rows 0..63, MQ=1 rows 64..127
#define LOAD_A(DST, BUF, MQ)                                                          \
  _Pragma("unroll") for (int mi = 0; mi < 4; ++mi)                                    \
  _Pragma("unroll") for (int kk = 0; kk < 2; ++kk)                                    \
    DST[mi][kk] = *(const bf16x8*)&lds[(BUF)*32768 + aWOff + (MQ)*4096 + mi*1024      \
                                       + rowoff + rcol[kk]];

// 16 MFMA: 4 mi x 2 ni x 2 kk -> acc[MB+mi][NB+ni]
#define MFMA16(AF, MB, BQ, NB)                                                        \
  _Pragma("unroll") for (int kk = 0; kk < 2; ++kk)                                    \
  _Pragma("unroll") for (int mi = 0; mi < 4; ++mi)                                    \
  _Pragma("unroll") for (int ni = 0; ni < 2; ++ni)                                    \
    acc[(MB)+mi][(NB)+ni] = __builtin_amdgcn_mfma_f32_16x16x32_bf16(                  \
        AF[mi][kk], BQ[ni][kk], acc[(MB)+mi][(NB)+ni], 0, 0, 0);

__global__ __launch_bounds__(512, 2) void k_gemm256(const unsigned short* __restrict__ A,
                                                    const unsigned short* __restrict__ B,
                                                    const float* __restrict__ bias,
                                                    const float* __restrict__ scale_p,
                                                    float* __restrict__ C) {
  extern __shared__ unsigned short lds[];

  const int nTn = NDIM / 256;                  // 43
  const int nwg = (MDIM / 256) * nTn;          // 1376 (== 0 mod 8)
  int wg = (int)blockIdx.x;
  wg = (wg & 7) * (nwg / 8) + (wg >> 3);       // XCD-aware swizzle (bijective)
  const int tm = wg / nTn;
  const int tn = wg % nTn;

  const int tid  = (int)threadIdx.x;
  const int lane = tid & 63;
  const int wave = tid >> 6;                   // 0..7
  const int wm   = wave >> 2;                  // 0..1  (M)
  const int wn   = wave & 3;                   // 0..3  (N)
  const int l15  = lane & 15;

  // read-side: row = l15 (+16-multiples), col = (hi*8 + kk*32) ^ ((l15&7)<<3)
  const int rowoff = l15 * 64;
  const int rsw = (l15 & 7) << 3;
  int rcol[2];
  rcol[0] = ((lane >> 4) * 8) ^ rsw;
  rcol[1] = ((lane >> 4) * 8 + 32) ^ rsw;
  // stage-side: LDS linear dest; pre-swizzled GLOBAL source column (rule #21)
  const int scol = ((tid & 7) * 8) ^ (((tid >> 3) & 7) << 3);
  const int srow = tid >> 3;                   // 0..63

  const int aWOff = wm * 8192;                             // this wave's A half
  const int bWOff = (wn >> 1) * 8192 + (wn & 1) * 4096;    // this wave's 64-row B chunk
  const int aRow = tm * 256;
  const int bRow = tn * 256;

  f32x4 acc[8][4];
  #pragma unroll
  for (int i = 0; i < 8; ++i)
    #pragma unroll
    for (int j = 0; j < 4; ++j) acc[i][j] = f32x4{0.f, 0.f, 0.f, 0.f};

  bf16x8 af[4][2], bq01[2][2], bq23[2][2];

  // ---- prologue: K0 -> buf0 (B h0,h1, A h0,h1); K1.B -> buf1 ----
  STAGE(B, bRow, 16384, 0, 0);
  STAGE(B, bRow, 16384, 1, 0);
  STAGE(A, aRow, 0,     0, 0);
  STAGE(A, aRow, 0,     1, 0);
  STAGE(B, bRow, 49152, 0, 1);
  STAGE(B, bRow, 49152, 1, 1);
  VM(4);                                        // buf0 K0 fully landed
  SB0();
  BAR();

  #pragma unroll 1
  for (int i = 0; i < 32; ++i) {
    const int kA = 2 * i + 1;                            // <= 63
    const int kB = (2 * i + 2 > 63) ? 63 : 2 * i + 2;    // clamped tail
    const int kC = (2 * i + 3 > 63) ? 63 : 2 * i + 3;
    // g0: buf0 reads B01 + Alow; stage buf1.A.h0 <- K(2i+1)
    LOAD_B2(bq01, 0, 0); LOAD_A(af, 0, 0);
    STAGE(A, aRow, 32768, 0, kA);
    BAR();
    PRIO1(); MFMA16(af, 0, bq01, 0); PRIO0(); SB0(); BAR();
    // g1: read B23; stage buf1.A.h1
    LOAD_B2(bq23, 0, 2);
    STAGE(A, aRow, 32768, 1, kA);
    BAR();
    PRIO1(); MFMA16(af, 0, bq23, 2); PRIO0(); SB0(); BAR();
    // g2: read Ahigh; stage buf0.B.h0 <- K(2i+2)
    LOAD_A(af, 0, 1);
    STAGE(B, bRow, 16384, 0, kB);
    BAR();
    PRIO1(); MFMA16(af, 4, bq23, 2); PRIO0(); SB0(); BAR();
    // g3: stage buf0.B.h1; counted vmcnt covers buf1 K(2i+1) before g4
    STAGE(B, bRow, 16384, 1, kB);
    BAR();
    PRIO1(); MFMA16(af, 4, bq01, 0); PRIO0();
    VM(4); SB0(); BAR();
    // g4: buf1 reads B01 + Alow; stage buf0.A.h0 <- K(2i+2)
    LOAD_B2(bq01, 1, 0); LOAD_A(af, 1, 0);
    STAGE(A, aRow, 0, 0, kB);
    BAR();
    PRIO1(); MFMA16(af, 0, bq01, 0); PRIO0(); SB0(); BAR();
    // g5: read B23; stage buf0.A.h1
    LOAD_B2(bq23, 1, 2);
    STAGE(A, aRow, 0, 1, kB);
    BAR();
    PRIO1(); MFMA16(af, 0, bq23, 2); PRIO0(); SB0(); BAR();
    // g6: read Ahigh; stage buf1.B.h0 <- K(2i+3)
    LOAD_A(af, 1, 1);
    STAGE(B, bRow, 49152, 0, kC);
    BAR();
    PRIO1(); MFMA16(af, 4, bq23, 2); PRIO0(); SB0(); BAR();
    // g7: stage buf1.B.h1; counted vmcnt covers buf0 K(2i+2) before next g0
    STAGE(B, bRow, 49152, 1, kC);
    BAR();
    PRIO1(); MFMA16(af, 4, bq01, 0); PRIO0();
    VM(4); SB0(); BAR();
  }

  VM(0);  // drain tail prefetch stages before epilogue

  const float sc = *scale_p;
  float bv[4];
  #pragma unroll
  for (int ni = 0; ni < 4; ++ni) bv[ni] = bias[tn * 256 + wn * 64 + ni * 16 + l15];

  // C/D layout: col = lane&15, row = (lane>>4)*4 + reg
  #pragma unroll
  for (int mi = 0; mi < 8; ++mi) {
    #pragma unroll
    for (int r = 0; r < 4; ++r) {
      const int m = tm * 256 + wm * 128 + mi * 16 + (lane >> 4) * 4 + r;
      float* crow = C + (size_t)m * NDIM + tn * 256 + wn * 64;
      #pragma unroll
      for (int ni = 0; ni < 4; ++ni)
        crow[ni * 16 + l15] = sc * acc[mi][ni][r] + bv[ni];
    }
  }
}

extern "C" void kernel_launch(void* const* d_in, const int* in_sizes, int n_in,
                              void* d_out, int out_size, void* d_ws, size_t ws_size,
                              hipStream_t stream) {
  const float* x = (const float*)d_in[0];
  const float* w = (const float*)d_in[1];
  const float* bias = (const float*)d_in[2];
  float* out = (float*)d_out;

  char* ws = (char*)d_ws;
  const size_t XB_BYTES = (size_t)MDIM * KDIM * 2;
  const size_t WQ_BYTES = (size_t)NDIM * KDIM * 2;
  unsigned short* xb = (unsigned short*)ws;
  unsigned short* wq = (unsigned short*)(ws + XB_BYTES);
  float* partials = (float*)(ws + XB_BYTES + WQ_BYTES);
  float* scale = partials + NBLK_W;

  k_convert_w<<<NBLK_W, 256, 0, stream>>>(w, wq, partials);
  k_scale<<<1, 256, 0, stream>>>(partials, scale);
  k_convert_x<<<NBLK_X, 256, 0, stream>>>(x, xb);

  (void)hipFuncSetAttribute((const void*)k_gemm256,
                            hipFuncAttributeMaxDynamicSharedMemorySize, 131072);
  const int grid = (MDIM / 256) * (NDIM / 256);  // 1376
  k_gemm256<<<grid, 512, 131072, stream>>>(xb, wq, bias, scale, out);
}